// Round 8
// baseline (455.118 us; speedup 1.0000x reference)
//
#include <hip/hip_runtime.h>
#include <math.h>

// ---- compile-time tables for the solid-harmonics recurrence ----
constexpr float C00f = 0.28209479177387814f;  // 1/sqrt(4*pi)

// AL[l] = -sqrt((2l+1)/(2l))
constexpr float AL[7] = {0.f,
  -1.22474487139158905f, -1.11803398874989485f, -1.08012344973464354f,
  -1.06066017177982121f, -1.04880884817015154f, -1.04083299973306640f};

// AINV[l][m] = 1/A(l,m), A(l,m)=sqrt((l^2-m^2)/((2l-1)(2l+1))), m<l
constexpr float AINV[7][7] = {
  {0,0,0,0,0,0,0},
  {1.73205080756887729f,0,0,0,0,0,0},
  {1.93649167310370852f,2.23606797749978969f,0,0,0,0,0},
  {1.97202659436653873f,2.09165006633518887f,2.64575131106459059f,0,0,0,0},
  {1.98431348329844304f,2.04939015319191986f,2.29128784747791999f,3.0f,0,0,0},
  {1.98997487421323993f,2.03100960115899020f,2.17124068443428311f,2.48746859276654987f,3.31662479035539985f,0,0},
  {1.99304345718356630f,2.02131499000000000f,2.11394180000000000f,2.30136840000000000f,2.67394840000000000f,3.60555127546398912f,0}
};

// APV[l][m] = A(l-1,m), valid for m <= l-2
constexpr float APV[7][7] = {
  {0,0,0,0,0,0,0},
  {0,0,0,0,0,0,0},
  {0.57735026918962576f,0,0,0,0,0,0},
  {0.51639777949432225f,0.44721359549995794f,0,0,0,0,0},
  {0.50709255283710986f,0.47809144373375745f,0.37796447300922722f,0,0,0,0},
  {0.50395263067896967f,0.48795003647426655f,0.43643578047198484f,0.33333333333333333f,0,0,0},
  {0.50251890762960643f,0.49236596391733095f,0.46056618647183828f,0.40201512610368484f,0.30151134457776363f,0,0}
};

// packed upper-triangle index for (a<=b), 6x6 -> 21
#define IDX21(a,b) ((a)*(11-(a))/2 + (b))

typedef float f4 __attribute__((ext_vector_type(4)));

// ---- PROBE A: linear grid-stride float4 sweep of the outdp region (junk).
// reps x 198 MB. Runs BEFORE the real pipeline; fully overwritten later.
__global__ __launch_bounds__(256) void k_probe_lin(float* __restrict__ out,
                                                   int n3, int reps) {
  f4* o = reinterpret_cast<f4*>(out + 252);
  unsigned total4 = 252u * ((unsigned)n3 / 4u);
  unsigned stride = gridDim.x * 256u;
  unsigned t0 = blockIdx.x * 256u + threadIdx.x;
  for (int r = 0; r < reps; ++r) {
    float v = (float)(t0 + (unsigned)r);
    f4 vv = {v, v + 1.f, v + 2.f, v + 3.f};
    for (unsigned i = t0; i < total4; i += stride) o[i] = vv;
  }
}

// ---- PROBE B: EXACT k_dp store pattern (256 blocks x 768 thr; per (l,g):
// plane 4g+pw, 3 KB chunk at colblk), junk values, no LDS/barriers.
// Isolates the ADDRESS PATTERN from k_dp's compute structure.
__global__ __launch_bounds__(768) void k_probe_sc(float* __restrict__ out,
                                                  int n3, int reps) {
  float* outdp = out + 252;
  const int tx  = threadIdx.x;
  const int wvi = tx >> 6;
  const int ln  = tx & 63;
  const int pw  = wvi / 3;
  const int qw  = wvi - 3*pw;
  const unsigned un3 = (unsigned)n3;
  const unsigned colblk = (unsigned)blockIdx.x * 768u;
  const unsigned coff = (unsigned)(qw*256 + (ln << 2));
  const unsigned col  = colblk + coff;
  for (int r = 0; r < reps; ++r) {
    float v = (float)(tx + r);
    f4 vv = {v, v, v, v};
    #pragma unroll
    for (int l = 0; l < 7; ++l) {
      #pragma unroll
      for (int g = 0; g < 9; ++g) {
        int p = g*4 + pw;                               // 0..35
        size_t planeoff = (size_t)(l*36 + p) * (size_t)un3;
        if (col + 4 <= un3)
          *reinterpret_cast<f4*>(outdp + planeoff + col) = vv;
      }
    }
  }
}

// ---- K0: zero the 294-float c accumulator in workspace (ws is poisoned 0xAA) ----
__global__ void k_zero(float* __restrict__ cg) {
  int t = blockIdx.x * 256 + threadIdx.x;
  if (t < 294) cg[t] = 0.f;
}

// 32-lane reduction (stays inside a half-wave -> ds_swizzle only, 5-deep chain)
__device__ __forceinline__ void red32_acc(float v, float* dst, int li) {
  v += __shfl_xor(v,  1, 32);
  v += __shfl_xor(v,  2, 32);
  v += __shfl_xor(v,  4, 32);
  v += __shfl_xor(v,  8, 32);
  v += __shfl_xor(v, 16, 32);
  if (li == 0) atomicAdd(dst, v);
}

// ---- K1: c[a,row,col] = sum_j f[a,j] * Ypacked[row,col,j]
// (round-1 proven version) Half-wave split: lanes 0-31 handle a in {0,1,2},
// lanes 32-63 handle a in {3,4,5} of the SAME 32 atoms.
__global__ __launch_bounds__(256) void k_accum_c(const float* __restrict__ xyz,
                                                 float* __restrict__ cg, int n) {
  __shared__ float cl[294];
  for (int i = threadIdx.x; i < 294; i += 256) cl[i] = 0.f;
  __syncthreads();
  int lane = threadIdx.x & 63;
  int wv   = threadIdx.x >> 6;      // wave in block: 0..3
  int li   = lane & 31;             // lane within half
  int half = lane >> 5;             // 0 -> a base 0, 1 -> a base 3
  int atom = blockIdx.x * 128 + wv * 32 + li;
  int ji = (atom < n) ? atom : 0;
  float x = xyz[3*ji+0], y = xyz[3*ji+1], z = xyz[3*ji+2];
  float r2 = x*x + y*y + z*z;
  float d  = sqrtf(r2);
  float tcut = 1.f - d * (1.f/6.f);
  float r = (d < 6.f && atom < n) ? tcut*tcut : 0.f;   // invalid lanes -> 0
  float r2c  = r2*r2*r2;
  float base = half ? (r*r2c) : r;          // f[a] = r * r2^a for this half's a's
  float fa[3];
  fa[0] = base; fa[1] = base*r2; fa[2] = fa[1]*r2;
  int abase = 3*half;

  float vr[2][7], vi[2][7];
  vr[0][0] = C00f; vi[0][0] = 0.f;
  #pragma unroll
  for (int l = 0; l <= 6; ++l) {
    const int cur = l & 1, prv = cur ^ 1;
    if (l > 0) {
      #pragma unroll
      for (int m = 0; m + 2 <= l; ++m) {      // two-term recurrence (prev2 in-place)
        float ai = AINV[l][m], ap = APV[l][m];
        vr[cur][m] = (z*vr[prv][m] - ap*r2*vr[cur][m]) * ai;
        vi[cur][m] = (z*vi[prv][m] - ap*r2*vi[cur][m]) * ai;
      }
      { float ai = AINV[l][l-1];              // one-term, m = l-1
        float vpr = vr[prv][l-1], vpi = vi[prv][l-1];
        vr[cur][l-1] = z*vpr*ai;
        vi[cur][l-1] = z*vpi*ai;
        vr[cur][l] = AL[l]*(x*vpr - y*vpi);   // diagonal m = l
        vi[cur][l] = AL[l]*(x*vpi + y*vpr); }
    }
    // re(l,m) -> packed (l, l-m); im(l,m>=1) -> packed (m-1, l)
    #pragma unroll
    for (int m = 0; m <= l; ++m) {
      int idx_re = l*7 + (l - m);
      #pragma unroll
      for (int i = 0; i < 3; ++i)
        red32_acc(fa[i]*vr[cur][m], &cl[(abase+i)*49 + idx_re], li);
      if (m >= 1) {
        int idx_im = (m-1)*7 + l;
        #pragma unroll
        for (int i = 0; i < 3; ++i)
          red32_acc(fa[i]*vi[cur][m], &cl[(abase+i)*49 + idx_im], li);
      }
    }
  }
  __syncthreads();
  for (int i = threadIdx.x; i < 294; i += 256) atomicAdd(&cg[i], cl[i]);
}

// ---- K3: dp[l,a,b,j,k] (+ p[l,a,b] folded into block 0) ----
// r5 structure: 768 cols/block, 12 waves, 1 block/CU, double-buffered 21-plane
// LDS panel, 4-planes-in-flight cooperative store (plain f4 stores, nt dropped).
__global__ __launch_bounds__(768) void k_dp(const float* __restrict__ xyz,
                                            const float* __restrict__ cg,
                                            float* __restrict__ out, int n3) {
  __shared__ float cs[294];
  __shared__ __align__(16) float sbuf[2][21 * 768];   // 129 KB double-buffered panel
  const int tx = threadIdx.x;
  for (int i = tx; i < 294; i += 768) {
    int rc  = i % 49;
    int row = rc / 7, col = rc % 7;
    float wgt = (row == col) ? 1.f : 2.f;   // packed diagonal = re(l,0)
    cs[i] = wgt * cg[i];
  }
  __syncthreads();

  // folded k_p: reads RAW cg from global (252 threads, L2-resident)
  if (blockIdx.x == 0 && tx < 252) {
    int t = tx;
    int pl = t / 36;
    int rem = t - 36*pl;
    int pa = rem / 6;
    int pb = rem - 6*pa;
    const float* ca = cg + pa*49;
    const float* cb = cg + pb*49;
    float s = 0.f;
    for (int mc = 0; mc <= pl; ++mc) {
      float wq = (mc == pl) ? 1.f : 2.f;
      s += wq * ca[pl*7+mc] * cb[pl*7+mc];
    }
    for (int rr = 0; rr < pl; ++rr)
      s += 2.f * ca[rr*7+pl] * cb[rr*7+pl];
    out[t] = s;
  }

  int tid = blockIdx.x * 768 + tx;
  // NO early return: all threads must reach the __syncthreads in the l-loop.
  int jj = (tid < n3) ? tid : (n3 - 1);     // clamp; invalid columns never stored
  int j = jj / 3;
  int k = jj - 3*j;
  float x = xyz[3*j+0], y = xyz[3*j+1], z = xyz[3*j+2];
  float ex = (k == 0) ? 1.f : 0.f;
  float ey = (k == 1) ? 1.f : 0.f;
  float ez = (k == 2) ? 1.f : 0.f;
  float pk = ex*x + ey*y + ez*z;       // xyz[k]
  float r2 = x*x + y*y + z*z;
  float d  = sqrtf(r2);
  float invd = (d > 0.f) ? 1.f/d : 0.f;
  bool inside = d < 6.f;
  float tcut = 1.f - d*(1.f/6.f);
  float r  = inside ? tcut*tcut : 0.f;
  float dr = inside ? (-1.f/3.f)*tcut : 0.f;
  float f[6], P[6];                    // f[a]; P[a] = (df[a]/dd) * xyz[k]/d
  float w = pk * invd;
  { float dp = 1.f;
    #pragma unroll
    for (int a = 0; a < 6; ++a) {
      f[a] = r*dp;
      P[a] = dp*(dr + (2.f*a)*r*invd) * w;
      dp *= r2;
    } }

  float* outdp = out + 252;
  const unsigned un3 = (unsigned)n3;
  const int wvi = tx >> 6;                 // wave index 0..11
  const int ln  = tx & 63;
  const unsigned colblk = (unsigned)blockIdx.x * 768u;
  const int pw  = wvi / 3;                 // plane sub-index 0..3 within group
  const int qw  = wvi - 3*pw;              // chunk 0..2 within the 3 KB span

  // value + d/dk recurrence, two rows ping-pong (row l-2 overwritten in place)
  float vr[2][7], vi[2][7], gr[2][7], gi[2][7];
  vr[0][0] = C00f; vi[0][0] = 0.f; gr[0][0] = 0.f; gi[0][0] = 0.f;
  #pragma unroll
  for (int l = 0; l <= 6; ++l) {
    const int cur = l & 1, prv = cur ^ 1;
    if (l > 0) {
      #pragma unroll
      for (int m = 0; m + 2 <= l; ++m) {
        float ai = AINV[l][m], ap = APV[l][m];
        float ovr = vr[cur][m], ovi = vi[cur][m];   // row l-2 (read before overwrite)
        float ogr = gr[cur][m], ogi = gi[cur][m];
        vr[cur][m] = (z*vr[prv][m] - ap*r2*ovr) * ai;
        gr[cur][m] = (ez*vr[prv][m] + z*gr[prv][m] - ap*(2.f*pk*ovr + r2*ogr)) * ai;
        vi[cur][m] = (z*vi[prv][m] - ap*r2*ovi) * ai;
        gi[cur][m] = (ez*vi[prv][m] + z*gi[prv][m] - ap*(2.f*pk*ovi + r2*ogi)) * ai;
      }
      { float ai  = AINV[l][l-1];
        float vpr = vr[prv][l-1], vpi = vi[prv][l-1];
        float gpr = gr[prv][l-1], gpi = gi[prv][l-1];
        vr[cur][l-1] = z*vpr*ai;
        gr[cur][l-1] = (ez*vpr + z*gpr)*ai;
        vi[cur][l-1] = z*vpi*ai;
        gi[cur][l-1] = (ez*vpi + z*gpi)*ai;
        vr[cur][l] = AL[l]*(x*vpr - y*vpi);
        gr[cur][l] = AL[l]*(ex*vpr + x*gpr - ey*vpi - y*gpi);
        vi[cur][l] = AL[l]*(x*vpi + y*vpr);
        gi[cur][l] = AL[l]*(ex*vpi + x*gpi + ey*vpr + y*gpr); }
    }
    // G[b] = masked Y*c for degree l; Hh[b] = same with dY/dk (weights pre-folded)
    float G[6]  = {0,0,0,0,0,0};
    float Hh[6] = {0,0,0,0,0,0};
    #pragma unroll
    for (int m = 0; m <= l; ++m) {
      float vv = vr[cur][m], gg = gr[cur][m];
      int base = l*7 + (l - m);
      #pragma unroll
      for (int b = 0; b < 6; ++b) { float cc = cs[b*49 + base]; G[b] += vv*cc; Hh[b] += gg*cc; }
      if (m >= 1) {
        float vv2 = vi[cur][m], gg2 = gi[cur][m];
        int base2 = (m-1)*7 + l;
        #pragma unroll
        for (int b = 0; b < 6; ++b) { float cc = cs[b*49 + base2]; G[b] += vv2*cc; Hh[b] += gg2*cc; }
      }
    }
    // stage the 21 unique symmetric planes for this block's 768 columns
    float* sb = sbuf[cur];
    #pragma unroll
    for (int a = 0; a < 6; ++a) {
      #pragma unroll
      for (int b = a; b < 6; ++b) {
        float val = P[a]*G[b] + f[a]*Hh[b] + P[b]*G[a] + f[b]*Hh[a];
        sb[IDX21(a,b)*768 + tx] = val;
      }
    }
    __syncthreads();
    // cooperative store, 4-planes-in-flight: group g covers planes 4g..4g+3;
    // wave w handles plane 4g + w/3, chunk (w%3)*1KB.
    #pragma unroll
    for (int g = 0; g < 9; ++g) {
      int p  = g*4 + pw;                  // 0..35
      int pa = p / 6, pb = p - 6*pa;
      int lo = pa < pb ? pa : pb;
      int hi = pa < pb ? pb : pa;
      unsigned coff = (unsigned)(qw*256 + (ln << 2));
      const float* sp = &sb[IDX21(lo,hi)*768 + coff];
      size_t planeoff = (size_t)(l*36 + p) * (size_t)un3;
      unsigned col = colblk + coff;
      if (col + 4 <= un3) {
        f4 v = *reinterpret_cast<const f4*>(sp);
        *reinterpret_cast<f4*>(outdp + planeoff + col) = v;
      } else {
        #pragma unroll
        for (int qq = 0; qq < 4; ++qq)
          if (col + qq < un3) outdp[planeoff + col + qq] = sp[coff + qq];
      }
    }
    // no second barrier: next l writes the OTHER buffer; the next iteration's
    // barrier orders reads-of-this-buffer vs the rewrite at l+2.
  }
}

extern "C" void kernel_launch(void* const* d_in, const int* in_sizes, int n_in,
                              void* d_out, int out_size, void* d_ws, size_t ws_size,
                              hipStream_t stream) {
  const float* xyz = (const float*)d_in[0];
  float* out = (float*)d_out;
  float* cg  = (float*)d_ws;      // 294 floats of scratch for c[a,row,col]
  int n3 = in_sizes[0];           // N*3 = 196608
  int n  = n3 / 3;                // N   = 65536

  // measurement probes (junk output, overwritten by the real pipeline below)
  k_probe_lin<<<dim3(2048),           dim3(256), 0, stream>>>(out, n3, 4);
  k_probe_sc <<<dim3(256),            dim3(768), 0, stream>>>(out, n3, 4);

  k_zero   <<<dim3(2),                dim3(256), 0, stream>>>(cg);
  k_accum_c<<<dim3((n + 127)/128),    dim3(256), 0, stream>>>(xyz, cg, n);
  k_dp     <<<dim3((n3 + 767)/768),   dim3(768), 0, stream>>>(xyz, cg, out, n3);
}

// Round 9
// 430.815 us; speedup vs baseline: 1.0564x; 1.0564x over previous
//
#include <hip/hip_runtime.h>
#include <math.h>

// ---- compile-time tables for the solid-harmonics recurrence ----
constexpr float C00f = 0.28209479177387814f;  // 1/sqrt(4*pi)

// AL[l] = -sqrt((2l+1)/(2l))
constexpr float AL[7] = {0.f,
  -1.22474487139158905f, -1.11803398874989485f, -1.08012344973464354f,
  -1.06066017177982121f, -1.04880884817015154f, -1.04083299973306640f};

// AINV[l][m] = 1/A(l,m), A(l,m)=sqrt((l^2-m^2)/((2l-1)(2l+1))), m<l
constexpr float AINV[7][7] = {
  {0,0,0,0,0,0,0},
  {1.73205080756887729f,0,0,0,0,0,0},
  {1.93649167310370852f,2.23606797749978969f,0,0,0,0,0},
  {1.97202659436653873f,2.09165006633518887f,2.64575131106459059f,0,0,0,0},
  {1.98431348329844304f,2.04939015319191986f,2.29128784747791999f,3.0f,0,0,0},
  {1.98997487421323993f,2.03100960115899020f,2.17124068443428311f,2.48746859276654987f,3.31662479035539985f,0,0},
  {1.99304345718356630f,2.02131499000000000f,2.11394180000000000f,2.30136840000000000f,2.67394840000000000f,3.60555127546398912f,0}
};

// APV[l][m] = A(l-1,m), valid for m <= l-2
constexpr float APV[7][7] = {
  {0,0,0,0,0,0,0},
  {0,0,0,0,0,0,0},
  {0.57735026918962576f,0,0,0,0,0,0},
  {0.51639777949432225f,0.44721359549995794f,0,0,0,0,0},
  {0.50709255283710986f,0.47809144373375745f,0.37796447300922722f,0,0,0,0},
  {0.50395263067896967f,0.48795003647426655f,0.43643578047198484f,0.33333333333333333f,0,0,0},
  {0.50251890762960643f,0.49236596391733095f,0.46056618647183828f,0.40201512610368484f,0.30151134457776363f,0,0}
};

// packed upper-triangle index for (a<=b), 6x6 -> 21
#define IDX21(a,b) ((a)*(11-(a))/2 + (b))

// measurement: repeat k_dp's full body (idempotent rewrites) to make its
// true duration directly visible in the top-5 dispatch table.
#define KDP_REPS 3

typedef float f4 __attribute__((ext_vector_type(4)));

// ---- K0: zero the 294-float c accumulator in workspace (ws is poisoned 0xAA) ----
__global__ void k_zero(float* __restrict__ cg) {
  int t = blockIdx.x * 256 + threadIdx.x;
  if (t < 294) cg[t] = 0.f;
}

// 32-lane reduction (stays inside a half-wave -> ds_swizzle only, 5-deep chain)
__device__ __forceinline__ void red32_acc(float v, float* dst, int li) {
  v += __shfl_xor(v,  1, 32);
  v += __shfl_xor(v,  2, 32);
  v += __shfl_xor(v,  4, 32);
  v += __shfl_xor(v,  8, 32);
  v += __shfl_xor(v, 16, 32);
  if (li == 0) atomicAdd(dst, v);
}

// ---- K1: c[a,row,col] = sum_j f[a,j] * Ypacked[row,col,j]
// (round-1 proven version) Half-wave split: lanes 0-31 handle a in {0,1,2},
// lanes 32-63 handle a in {3,4,5} of the SAME 32 atoms.
__global__ __launch_bounds__(256) void k_accum_c(const float* __restrict__ xyz,
                                                 float* __restrict__ cg, int n) {
  __shared__ float cl[294];
  for (int i = threadIdx.x; i < 294; i += 256) cl[i] = 0.f;
  __syncthreads();
  int lane = threadIdx.x & 63;
  int wv   = threadIdx.x >> 6;      // wave in block: 0..3
  int li   = lane & 31;             // lane within half
  int half = lane >> 5;             // 0 -> a base 0, 1 -> a base 3
  int atom = blockIdx.x * 128 + wv * 32 + li;
  int ji = (atom < n) ? atom : 0;
  float x = xyz[3*ji+0], y = xyz[3*ji+1], z = xyz[3*ji+2];
  float r2 = x*x + y*y + z*z;
  float d  = sqrtf(r2);
  float tcut = 1.f - d * (1.f/6.f);
  float r = (d < 6.f && atom < n) ? tcut*tcut : 0.f;   // invalid lanes -> 0
  float r2c  = r2*r2*r2;
  float base = half ? (r*r2c) : r;          // f[a] = r * r2^a for this half's a's
  float fa[3];
  fa[0] = base; fa[1] = base*r2; fa[2] = fa[1]*r2;
  int abase = 3*half;

  float vr[2][7], vi[2][7];
  vr[0][0] = C00f; vi[0][0] = 0.f;
  #pragma unroll
  for (int l = 0; l <= 6; ++l) {
    const int cur = l & 1, prv = cur ^ 1;
    if (l > 0) {
      #pragma unroll
      for (int m = 0; m + 2 <= l; ++m) {      // two-term recurrence (prev2 in-place)
        float ai = AINV[l][m], ap = APV[l][m];
        vr[cur][m] = (z*vr[prv][m] - ap*r2*vr[cur][m]) * ai;
        vi[cur][m] = (z*vi[prv][m] - ap*r2*vi[cur][m]) * ai;
      }
      { float ai = AINV[l][l-1];              // one-term, m = l-1
        float vpr = vr[prv][l-1], vpi = vi[prv][l-1];
        vr[cur][l-1] = z*vpr*ai;
        vi[cur][l-1] = z*vpi*ai;
        vr[cur][l] = AL[l]*(x*vpr - y*vpi);   // diagonal m = l
        vi[cur][l] = AL[l]*(x*vpi + y*vpr); }
    }
    // re(l,m) -> packed (l, l-m); im(l,m>=1) -> packed (m-1, l)
    #pragma unroll
    for (int m = 0; m <= l; ++m) {
      int idx_re = l*7 + (l - m);
      #pragma unroll
      for (int i = 0; i < 3; ++i)
        red32_acc(fa[i]*vr[cur][m], &cl[(abase+i)*49 + idx_re], li);
      if (m >= 1) {
        int idx_im = (m-1)*7 + l;
        #pragma unroll
        for (int i = 0; i < 3; ++i)
          red32_acc(fa[i]*vi[cur][m], &cl[(abase+i)*49 + idx_im], li);
      }
    }
  }
  __syncthreads();
  for (int i = threadIdx.x; i < 294; i += 256) atomicAdd(&cg[i], cl[i]);
}

// ---- K3: dp[l,a,b,j,k] (+ p[l,a,b] folded into block 0) ----
// r5 structure: 768 cols/block, 12 waves, 1 block/CU, double-buffered 21-plane
// LDS panel, 4-planes-in-flight cooperative store. THIS ROUND: the full
// compute+store body repeats KDP_REPS times (idempotent) so k_dp's true
// duration appears directly in the profile.
__global__ __launch_bounds__(768) void k_dp(const float* __restrict__ xyz,
                                            const float* __restrict__ cg,
                                            float* __restrict__ out, int n3) {
  __shared__ float cs[294];
  __shared__ __align__(16) float sbuf[2][21 * 768];   // 129 KB double-buffered panel
  const int tx = threadIdx.x;
  for (int i = tx; i < 294; i += 768) {
    int rc  = i % 49;
    int row = rc / 7, col = rc % 7;
    float wgt = (row == col) ? 1.f : 2.f;   // packed diagonal = re(l,0)
    cs[i] = wgt * cg[i];
  }
  __syncthreads();

  // folded k_p: reads RAW cg from global (252 threads, L2-resident)
  if (blockIdx.x == 0 && tx < 252) {
    int t = tx;
    int pl = t / 36;
    int rem = t - 36*pl;
    int pa = rem / 6;
    int pb = rem - 6*pa;
    const float* ca = cg + pa*49;
    const float* cb = cg + pb*49;
    float s = 0.f;
    for (int mc = 0; mc <= pl; ++mc) {
      float wq = (mc == pl) ? 1.f : 2.f;
      s += wq * ca[pl*7+mc] * cb[pl*7+mc];
    }
    for (int rr = 0; rr < pl; ++rr)
      s += 2.f * ca[rr*7+pl] * cb[rr*7+pl];
    out[t] = s;
  }

  int tid = blockIdx.x * 768 + tx;
  // NO early return: all threads must reach the __syncthreads in the l-loop.
  int jj = (tid < n3) ? tid : (n3 - 1);     // clamp; invalid columns never stored
  int j = jj / 3;
  int k = jj - 3*j;
  float x = xyz[3*j+0], y = xyz[3*j+1], z = xyz[3*j+2];
  float ex = (k == 0) ? 1.f : 0.f;
  float ey = (k == 1) ? 1.f : 0.f;
  float ez = (k == 2) ? 1.f : 0.f;
  float pk = ex*x + ey*y + ez*z;       // xyz[k]
  float r2 = x*x + y*y + z*z;
  float d  = sqrtf(r2);
  float invd = (d > 0.f) ? 1.f/d : 0.f;
  bool inside = d < 6.f;
  float tcut = 1.f - d*(1.f/6.f);
  float r  = inside ? tcut*tcut : 0.f;
  float dr = inside ? (-1.f/3.f)*tcut : 0.f;
  float f[6], P[6];                    // f[a]; P[a] = (df[a]/dd) * xyz[k]/d
  float w = pk * invd;
  { float dp = 1.f;
    #pragma unroll
    for (int a = 0; a < 6; ++a) {
      f[a] = r*dp;
      P[a] = dp*(dr + (2.f*a)*r*invd) * w;
      dp *= r2;
    } }

  float* outdp = out + 252;
  const unsigned un3 = (unsigned)n3;
  const int wvi = tx >> 6;                 // wave index 0..11
  const int ln  = tx & 63;
  const unsigned colblk = (unsigned)blockIdx.x * 768u;
  const int pw  = wvi / 3;                 // plane sub-index 0..3 within group
  const int qw  = wvi - 3*pw;              // chunk 0..2 within the 3 KB span

  for (int rep = 0; rep < KDP_REPS; ++rep) {
    // value + d/dk recurrence, two rows ping-pong (row l-2 overwritten in place)
    float vr[2][7], vi[2][7], gr[2][7], gi[2][7];
    vr[0][0] = C00f; vi[0][0] = 0.f; gr[0][0] = 0.f; gi[0][0] = 0.f;
    #pragma unroll
    for (int l = 0; l <= 6; ++l) {
      const int cur = l & 1, prv = cur ^ 1;
      if (l > 0) {
        #pragma unroll
        for (int m = 0; m + 2 <= l; ++m) {
          float ai = AINV[l][m], ap = APV[l][m];
          float ovr = vr[cur][m], ovi = vi[cur][m];   // row l-2 (read before overwrite)
          float ogr = gr[cur][m], ogi = gi[cur][m];
          vr[cur][m] = (z*vr[prv][m] - ap*r2*ovr) * ai;
          gr[cur][m] = (ez*vr[prv][m] + z*gr[prv][m] - ap*(2.f*pk*ovr + r2*ogr)) * ai;
          vi[cur][m] = (z*vi[prv][m] - ap*r2*ovi) * ai;
          gi[cur][m] = (ez*vi[prv][m] + z*gi[prv][m] - ap*(2.f*pk*ovi + r2*ogi)) * ai;
        }
        { float ai  = AINV[l][l-1];
          float vpr = vr[prv][l-1], vpi = vi[prv][l-1];
          float gpr = gr[prv][l-1], gpi = gi[prv][l-1];
          vr[cur][l-1] = z*vpr*ai;
          gr[cur][l-1] = (ez*vpr + z*gpr)*ai;
          vi[cur][l-1] = z*vpi*ai;
          gi[cur][l-1] = (ez*vpi + z*gpi)*ai;
          vr[cur][l] = AL[l]*(x*vpr - y*vpi);
          gr[cur][l] = AL[l]*(ex*vpr + x*gpr - ey*vpi - y*gpi);
          vi[cur][l] = AL[l]*(x*vpi + y*vpr);
          gi[cur][l] = AL[l]*(ex*vpi + x*gpi + ey*vpr + y*gpr); }
      }
      // G[b] = masked Y*c for degree l; Hh[b] = same with dY/dk (weights pre-folded)
      float G[6]  = {0,0,0,0,0,0};
      float Hh[6] = {0,0,0,0,0,0};
      #pragma unroll
      for (int m = 0; m <= l; ++m) {
        float vv = vr[cur][m], gg = gr[cur][m];
        int base = l*7 + (l - m);
        #pragma unroll
        for (int b = 0; b < 6; ++b) { float cc = cs[b*49 + base]; G[b] += vv*cc; Hh[b] += gg*cc; }
        if (m >= 1) {
          float vv2 = vi[cur][m], gg2 = gi[cur][m];
          int base2 = (m-1)*7 + l;
          #pragma unroll
          for (int b = 0; b < 6; ++b) { float cc = cs[b*49 + base2]; G[b] += vv2*cc; Hh[b] += gg2*cc; }
        }
      }
      // stage the 21 unique symmetric planes for this block's 768 columns
      float* sb = sbuf[cur];
      #pragma unroll
      for (int a = 0; a < 6; ++a) {
        #pragma unroll
        for (int b = a; b < 6; ++b) {
          float val = P[a]*G[b] + f[a]*Hh[b] + P[b]*G[a] + f[b]*Hh[a];
          sb[IDX21(a,b)*768 + tx] = val;
        }
      }
      __syncthreads();
      // cooperative store, 4-planes-in-flight: group g covers planes 4g..4g+3;
      // wave w handles plane 4g + w/3, chunk (w%3)*1KB.
      #pragma unroll
      for (int g = 0; g < 9; ++g) {
        int p  = g*4 + pw;                  // 0..35
        int pa = p / 6, pb = p - 6*pa;
        int lo = pa < pb ? pa : pb;
        int hi = pa < pb ? pb : pa;
        unsigned coff = (unsigned)(qw*256 + (ln << 2));
        const float* sp = &sb[IDX21(lo,hi)*768 + coff];
        size_t planeoff = (size_t)(l*36 + p) * (size_t)un3;
        unsigned col = colblk + coff;
        if (col + 4 <= un3) {
          f4 v = *reinterpret_cast<const f4*>(sp);
          *reinterpret_cast<f4*>(outdp + planeoff + col) = v;
        } else {
          #pragma unroll
          for (int qq = 0; qq < 4; ++qq)
            if (col + qq < un3) outdp[planeoff + col + qq] = sp[coff + qq];
        }
      }
      // no second barrier inside the l-loop: next l writes the OTHER buffer;
      // the next iteration's barrier orders reads vs the rewrite at l+2.
    }
    // cross-rep hazard: rep r+1's l=0 staging reuses sbuf[0] which rep r's
    // l=6 stores read; close it with one barrier per rep.
    __syncthreads();
  }
}

extern "C" void kernel_launch(void* const* d_in, const int* in_sizes, int n_in,
                              void* d_out, int out_size, void* d_ws, size_t ws_size,
                              hipStream_t stream) {
  const float* xyz = (const float*)d_in[0];
  float* out = (float*)d_out;
  float* cg  = (float*)d_ws;      // 294 floats of scratch for c[a,row,col]
  int n3 = in_sizes[0];           // N*3 = 196608
  int n  = n3 / 3;                // N   = 65536

  k_zero   <<<dim3(2),               dim3(256), 0, stream>>>(cg);
  k_accum_c<<<dim3((n + 127)/128),   dim3(256), 0, stream>>>(xyz, cg, n);
  k_dp     <<<dim3((n3 + 767)/768),  dim3(768), 0, stream>>>(xyz, cg, out, n3);
}

// Round 10
// 236.468 us; speedup vs baseline: 1.9247x; 1.8219x over previous
//
#include <hip/hip_runtime.h>
#include <math.h>

// ---- compile-time tables for the solid-harmonics recurrence ----
constexpr float C00f = 0.28209479177387814f;  // 1/sqrt(4*pi)

// AL[l] = -sqrt((2l+1)/(2l))
constexpr float AL[7] = {0.f,
  -1.22474487139158905f, -1.11803398874989485f, -1.08012344973464354f,
  -1.06066017177982121f, -1.04880884817015154f, -1.04083299973306640f};

// AINV[l][m] = 1/A(l,m), A(l,m)=sqrt((l^2-m^2)/((2l-1)(2l+1))), m<l
constexpr float AINV[7][7] = {
  {0,0,0,0,0,0,0},
  {1.73205080756887729f,0,0,0,0,0,0},
  {1.93649167310370852f,2.23606797749978969f,0,0,0,0,0},
  {1.97202659436653873f,2.09165006633518887f,2.64575131106459059f,0,0,0,0},
  {1.98431348329844304f,2.04939015319191986f,2.29128784747791999f,3.0f,0,0,0},
  {1.98997487421323993f,2.03100960115899020f,2.17124068443428311f,2.48746859276654987f,3.31662479035539985f,0,0},
  {1.99304345718356630f,2.02131499000000000f,2.11394180000000000f,2.30136840000000000f,2.67394840000000000f,3.60555127546398912f,0}
};

// APV[l][m] = A(l-1,m), valid for m <= l-2
constexpr float APV[7][7] = {
  {0,0,0,0,0,0,0},
  {0,0,0,0,0,0,0},
  {0.57735026918962576f,0,0,0,0,0,0},
  {0.51639777949432225f,0.44721359549995794f,0,0,0,0,0},
  {0.50709255283710986f,0.47809144373375745f,0.37796447300922722f,0,0,0,0},
  {0.50395263067896967f,0.48795003647426655f,0.43643578047198484f,0.33333333333333333f,0,0,0},
  {0.50251890762960643f,0.49236596391733095f,0.46056618647183828f,0.40201512610368484f,0.30151134457776363f,0,0}
};

// packed upper-triangle index for (a<=b), 6x6 -> 21
#define IDX21(a,b) ((a)*(11-(a))/2 + (b))

typedef float f4 __attribute__((ext_vector_type(4)));

// LDS-only barrier: drain this wave's LDS ops, then raw s_barrier.
// Deliberately does NOT drain vmcnt -> global stores stay in flight across
// iterations (the compiler's __syncthreads would emit s_waitcnt vmcnt(0)).
__device__ __forceinline__ void lds_barrier() {
  asm volatile("s_waitcnt lgkmcnt(0)" ::: "memory");
  __builtin_amdgcn_s_barrier();
}

// ---- K0: zero the 294-float c accumulator in workspace (ws is poisoned 0xAA) ----
__global__ void k_zero(float* __restrict__ cg) {
  int t = blockIdx.x * 256 + threadIdx.x;
  if (t < 294) cg[t] = 0.f;
}

// 32-lane reduction (stays inside a half-wave -> ds_swizzle only, 5-deep chain)
__device__ __forceinline__ void red32_acc(float v, float* dst, int li) {
  v += __shfl_xor(v,  1, 32);
  v += __shfl_xor(v,  2, 32);
  v += __shfl_xor(v,  4, 32);
  v += __shfl_xor(v,  8, 32);
  v += __shfl_xor(v, 16, 32);
  if (li == 0) atomicAdd(dst, v);
}

// ---- K1: c[a,row,col] = sum_j f[a,j] * Ypacked[row,col,j]
// (round-1 proven version) Half-wave split: lanes 0-31 handle a in {0,1,2},
// lanes 32-63 handle a in {3,4,5} of the SAME 32 atoms.
__global__ __launch_bounds__(256) void k_accum_c(const float* __restrict__ xyz,
                                                 float* __restrict__ cg, int n) {
  __shared__ float cl[294];
  for (int i = threadIdx.x; i < 294; i += 256) cl[i] = 0.f;
  __syncthreads();
  int lane = threadIdx.x & 63;
  int wv   = threadIdx.x >> 6;      // wave in block: 0..3
  int li   = lane & 31;             // lane within half
  int half = lane >> 5;             // 0 -> a base 0, 1 -> a base 3
  int atom = blockIdx.x * 128 + wv * 32 + li;
  int ji = (atom < n) ? atom : 0;
  float x = xyz[3*ji+0], y = xyz[3*ji+1], z = xyz[3*ji+2];
  float r2 = x*x + y*y + z*z;
  float d  = sqrtf(r2);
  float tcut = 1.f - d * (1.f/6.f);
  float r = (d < 6.f && atom < n) ? tcut*tcut : 0.f;   // invalid lanes -> 0
  float r2c  = r2*r2*r2;
  float base = half ? (r*r2c) : r;          // f[a] = r * r2^a for this half's a's
  float fa[3];
  fa[0] = base; fa[1] = base*r2; fa[2] = fa[1]*r2;
  int abase = 3*half;

  float vr[2][7], vi[2][7];
  vr[0][0] = C00f; vi[0][0] = 0.f;
  #pragma unroll
  for (int l = 0; l <= 6; ++l) {
    const int cur = l & 1, prv = cur ^ 1;
    if (l > 0) {
      #pragma unroll
      for (int m = 0; m + 2 <= l; ++m) {      // two-term recurrence (prev2 in-place)
        float ai = AINV[l][m], ap = APV[l][m];
        vr[cur][m] = (z*vr[prv][m] - ap*r2*vr[cur][m]) * ai;
        vi[cur][m] = (z*vi[prv][m] - ap*r2*vi[cur][m]) * ai;
      }
      { float ai = AINV[l][l-1];              // one-term, m = l-1
        float vpr = vr[prv][l-1], vpi = vi[prv][l-1];
        vr[cur][l-1] = z*vpr*ai;
        vi[cur][l-1] = z*vpi*ai;
        vr[cur][l] = AL[l]*(x*vpr - y*vpi);   // diagonal m = l
        vi[cur][l] = AL[l]*(x*vpi + y*vpr); }
    }
    // re(l,m) -> packed (l, l-m); im(l,m>=1) -> packed (m-1, l)
    #pragma unroll
    for (int m = 0; m <= l; ++m) {
      int idx_re = l*7 + (l - m);
      #pragma unroll
      for (int i = 0; i < 3; ++i)
        red32_acc(fa[i]*vr[cur][m], &cl[(abase+i)*49 + idx_re], li);
      if (m >= 1) {
        int idx_im = (m-1)*7 + l;
        #pragma unroll
        for (int i = 0; i < 3; ++i)
          red32_acc(fa[i]*vi[cur][m], &cl[(abase+i)*49 + idx_im], li);
      }
    }
  }
  __syncthreads();
  for (int i = threadIdx.x; i < 294; i += 256) atomicAdd(&cg[i], cl[i]);
}

// ---- K3: dp[l,a,b,j,k] (+ p[l,a,b] folded into block 0) ----
// r5 structure: 768 cols/block, 12 waves, 1 block/CU, double-buffered 21-plane
// LDS panel, 4-planes-in-flight cooperative store. THIS ROUND: in-loop
// __syncthreads replaced by lds_barrier() (lgkmcnt-only drain + raw s_barrier)
// so global stores stay in flight across all 7 l-iterations (T4: never drain
// vmcnt to 0 in the loop). r9 measured the __syncthreads version at 81 us/rep
// = 2.8 TB/s; the same address pattern with free-flowing stores (k_probe_sc,
// r8) runs at 6.65 TB/s.
__global__ __launch_bounds__(768) void k_dp(const float* __restrict__ xyz,
                                            const float* __restrict__ cg,
                                            float* __restrict__ out, int n3) {
  __shared__ float cs[294];
  __shared__ __align__(16) float sbuf[2][21 * 768];   // 129 KB double-buffered panel
  const int tx = threadIdx.x;
  for (int i = tx; i < 294; i += 768) {
    int rc  = i % 49;
    int row = rc / 7, col = rc % 7;
    float wgt = (row == col) ? 1.f : 2.f;   // packed diagonal = re(l,0)
    cs[i] = wgt * cg[i];
  }
  __syncthreads();   // one-time; no stores in flight yet, drain is free

  // folded k_p: reads RAW cg from global (252 threads, L2-resident)
  if (blockIdx.x == 0 && tx < 252) {
    int t = tx;
    int pl = t / 36;
    int rem = t - 36*pl;
    int pa = rem / 6;
    int pb = rem - 6*pa;
    const float* ca = cg + pa*49;
    const float* cb = cg + pb*49;
    float s = 0.f;
    for (int mc = 0; mc <= pl; ++mc) {
      float wq = (mc == pl) ? 1.f : 2.f;
      s += wq * ca[pl*7+mc] * cb[pl*7+mc];
    }
    for (int rr = 0; rr < pl; ++rr)
      s += 2.f * ca[rr*7+pl] * cb[rr*7+pl];
    out[t] = s;
  }

  int tid = blockIdx.x * 768 + tx;
  // NO early return: all threads must reach the barriers in the l-loop.
  int jj = (tid < n3) ? tid : (n3 - 1);     // clamp; invalid columns never stored
  int j = jj / 3;
  int k = jj - 3*j;
  float x = xyz[3*j+0], y = xyz[3*j+1], z = xyz[3*j+2];
  float ex = (k == 0) ? 1.f : 0.f;
  float ey = (k == 1) ? 1.f : 0.f;
  float ez = (k == 2) ? 1.f : 0.f;
  float pk = ex*x + ey*y + ez*z;       // xyz[k]
  float r2 = x*x + y*y + z*z;
  float d  = sqrtf(r2);
  float invd = (d > 0.f) ? 1.f/d : 0.f;
  bool inside = d < 6.f;
  float tcut = 1.f - d*(1.f/6.f);
  float r  = inside ? tcut*tcut : 0.f;
  float dr = inside ? (-1.f/3.f)*tcut : 0.f;
  float f[6], P[6];                    // f[a]; P[a] = (df[a]/dd) * xyz[k]/d
  float w = pk * invd;
  { float dp = 1.f;
    #pragma unroll
    for (int a = 0; a < 6; ++a) {
      f[a] = r*dp;
      P[a] = dp*(dr + (2.f*a)*r*invd) * w;
      dp *= r2;
    } }

  float* outdp = out + 252;
  const unsigned un3 = (unsigned)n3;
  const int wvi = tx >> 6;                 // wave index 0..11
  const int ln  = tx & 63;
  const unsigned colblk = (unsigned)blockIdx.x * 768u;
  const int pw  = wvi / 3;                 // plane sub-index 0..3 within group
  const int qw  = wvi - 3*pw;              // chunk 0..2 within the 3 KB span

  // value + d/dk recurrence, two rows ping-pong (row l-2 overwritten in place)
  float vr[2][7], vi[2][7], gr[2][7], gi[2][7];
  vr[0][0] = C00f; vi[0][0] = 0.f; gr[0][0] = 0.f; gi[0][0] = 0.f;
  #pragma unroll
  for (int l = 0; l <= 6; ++l) {
    const int cur = l & 1, prv = cur ^ 1;
    if (l > 0) {
      #pragma unroll
      for (int m = 0; m + 2 <= l; ++m) {
        float ai = AINV[l][m], ap = APV[l][m];
        float ovr = vr[cur][m], ovi = vi[cur][m];   // row l-2 (read before overwrite)
        float ogr = gr[cur][m], ogi = gi[cur][m];
        vr[cur][m] = (z*vr[prv][m] - ap*r2*ovr) * ai;
        gr[cur][m] = (ez*vr[prv][m] + z*gr[prv][m] - ap*(2.f*pk*ovr + r2*ogr)) * ai;
        vi[cur][m] = (z*vi[prv][m] - ap*r2*ovi) * ai;
        gi[cur][m] = (ez*vi[prv][m] + z*gi[prv][m] - ap*(2.f*pk*ovi + r2*ogi)) * ai;
      }
      { float ai  = AINV[l][l-1];
        float vpr = vr[prv][l-1], vpi = vi[prv][l-1];
        float gpr = gr[prv][l-1], gpi = gi[prv][l-1];
        vr[cur][l-1] = z*vpr*ai;
        gr[cur][l-1] = (ez*vpr + z*gpr)*ai;
        vi[cur][l-1] = z*vpi*ai;
        gi[cur][l-1] = (ez*vpi + z*gpi)*ai;
        vr[cur][l] = AL[l]*(x*vpr - y*vpi);
        gr[cur][l] = AL[l]*(ex*vpr + x*gpr - ey*vpi - y*gpi);
        vi[cur][l] = AL[l]*(x*vpi + y*vpr);
        gi[cur][l] = AL[l]*(ex*vpi + x*gpi + ey*vpr + y*gpr); }
    }
    // G[b] = masked Y*c for degree l; Hh[b] = same with dY/dk (weights pre-folded)
    float G[6]  = {0,0,0,0,0,0};
    float Hh[6] = {0,0,0,0,0,0};
    #pragma unroll
    for (int m = 0; m <= l; ++m) {
      float vv = vr[cur][m], gg = gr[cur][m];
      int base = l*7 + (l - m);
      #pragma unroll
      for (int b = 0; b < 6; ++b) { float cc = cs[b*49 + base]; G[b] += vv*cc; Hh[b] += gg*cc; }
      if (m >= 1) {
        float vv2 = vi[cur][m], gg2 = gi[cur][m];
        int base2 = (m-1)*7 + l;
        #pragma unroll
        for (int b = 0; b < 6; ++b) { float cc = cs[b*49 + base2]; G[b] += vv2*cc; Hh[b] += gg2*cc; }
      }
    }
    // stage the 21 unique symmetric planes for this block's 768 columns
    float* sb = sbuf[cur];
    #pragma unroll
    for (int a = 0; a < 6; ++a) {
      #pragma unroll
      for (int b = a; b < 6; ++b) {
        float val = P[a]*G[b] + f[a]*Hh[b] + P[b]*G[a] + f[b]*Hh[a];
        sb[IDX21(a,b)*768 + tx] = val;
      }
    }
    // LDS-only barrier: this wave's ds_writes (and its ds_reads of the buffer
    // being reused at l+1, issued at l-1) are drained; global stores are NOT.
    lds_barrier();
    // cooperative store, 4-planes-in-flight: group g covers planes 4g..4g+3;
    // wave w handles plane 4g + w/3, chunk (w%3)*1KB. vmcnt accumulates;
    // compiler inserts counted waits only for register reuse.
    #pragma unroll
    for (int g = 0; g < 9; ++g) {
      int p  = g*4 + pw;                  // 0..35
      int pa = p / 6, pb = p - 6*pa;
      int lo = pa < pb ? pa : pb;
      int hi = pa < pb ? pb : pa;
      unsigned coff = (unsigned)(qw*256 + (ln << 2));
      const float* sp = &sb[IDX21(lo,hi)*768 + coff];
      size_t planeoff = (size_t)(l*36 + p) * (size_t)un3;
      unsigned col = colblk + coff;
      if (col + 4 <= un3) {
        f4 v = *reinterpret_cast<const f4*>(sp);
        *reinterpret_cast<f4*>(outdp + planeoff + col) = v;
      } else {
        #pragma unroll
        for (int qq = 0; qq < 4; ++qq)
          if (col + qq < un3) outdp[planeoff + col + qq] = sp[coff + qq];
      }
    }
    // no second barrier: next l writes the OTHER buffer; the next iteration's
    // lds_barrier orders reads-of-this-buffer vs the rewrite at l+2.
  }
}

extern "C" void kernel_launch(void* const* d_in, const int* in_sizes, int n_in,
                              void* d_out, int out_size, void* d_ws, size_t ws_size,
                              hipStream_t stream) {
  const float* xyz = (const float*)d_in[0];
  float* out = (float*)d_out;
  float* cg  = (float*)d_ws;      // 294 floats of scratch for c[a,row,col]
  int n3 = in_sizes[0];           // N*3 = 196608
  int n  = n3 / 3;                // N   = 65536

  k_zero   <<<dim3(2),               dim3(256), 0, stream>>>(cg);
  k_accum_c<<<dim3((n + 127)/128),   dim3(256), 0, stream>>>(xyz, cg, n);
  k_dp     <<<dim3((n3 + 767)/768),  dim3(768), 0, stream>>>(xyz, cg, out, n3);
}